// Round 5
// baseline (376.468 us; speedup 1.0000x reference)
//
#include <hip/hip_runtime.h>
#include <hip/hip_bf16.h>

#define Bc 2
#define Tc 2048
#define Dc 1024
#define Hc 16
#define Mc (Bc*Tc)   // 4096
#define QB 64
#define KB 32

typedef __attribute__((ext_vector_type(8))) short bf16x8;
typedef __attribute__((ext_vector_type(4))) short bf16x4;
typedef __attribute__((ext_vector_type(4))) float fx4;

__device__ __forceinline__ short f2bf(float f) {
  __hip_bfloat16 h = __float2bfloat16(f);
  return *reinterpret_cast<short*>(&h);
}

// ---------------------------------------------------------------------------
// merged small fp32 GEMMs: z=0..3 -> N=64 (w1w,w2w,w1r,w2r), z=4 -> N=16 gate
// ---------------------------------------------------------------------------
__global__ __launch_bounds__(256) void gemm_small_k(
    const float* __restrict__ A,
    const float* __restrict__ W0, const float* __restrict__ W1,
    const float* __restrict__ W2, const float* __restrict__ W3,
    const float* __restrict__ W4, const float* __restrict__ b4,
    float* __restrict__ O0, float* __restrict__ O1,
    float* __restrict__ O2, float* __restrict__ O3, float* __restrict__ O4)
{
  const int z = blockIdx.x;
  const float* W; float* O; int N; const float* bias = nullptr;
  if      (z == 0) { W = W0; O = O0; N = 64; }
  else if (z == 1) { W = W1; O = O1; N = 64; }
  else if (z == 2) { W = W2; O = O2; N = 64; }
  else if (z == 3) { W = W3; O = O3; N = 64; }
  else             { W = W4; O = O4; N = 16; bias = b4; }

  __shared__ float As[16][68];
  __shared__ float Ws[16][68];
  const int row0 = blockIdx.y * 64;
  const int tid  = threadIdx.x;
  const int tx = tid & 15, ty = tid >> 4;
  const int K = 1024;

  float acc[4][4] = {};

  for (int k0 = 0; k0 < K; k0 += 16) {
    {
      const int r  = tid >> 2;
      const int kc = (tid & 3) * 4;
      const float4 a4 = *(const float4*)&A[(size_t)(row0 + r) * K + k0 + kc];
      As[kc + 0][r] = a4.x; As[kc + 1][r] = a4.y;
      As[kc + 2][r] = a4.z; As[kc + 3][r] = a4.w;
    }
    {
      const int kr = tid >> 4;
      const int c  = (tid & 15) * 4;
      float4 w4 = make_float4(0.f, 0.f, 0.f, 0.f);
      if (c + 3 < N) {
        w4 = *(const float4*)&W[(size_t)(k0 + kr) * N + c];
      } else if (c < N) {
        w4.x = W[(size_t)(k0 + kr) * N + c];
        if (c + 1 < N) w4.y = W[(size_t)(k0 + kr) * N + c + 1];
        if (c + 2 < N) w4.z = W[(size_t)(k0 + kr) * N + c + 2];
      }
      *(float4*)&Ws[kr][c] = w4;
    }
    __syncthreads();
    #pragma unroll
    for (int kk = 0; kk < 16; kk++) {
      const float4 a4 = *(const float4*)&As[kk][ty * 4];
      const float4 w4 = *(const float4*)&Ws[kk][tx * 4];
      const float a[4] = {a4.x, a4.y, a4.z, a4.w};
      const float w[4] = {w4.x, w4.y, w4.z, w4.w};
      #pragma unroll
      for (int i = 0; i < 4; i++)
        #pragma unroll
        for (int j = 0; j < 4; j++)
          acc[i][j] = fmaf(a[i], w[j], acc[i][j]);
    }
    __syncthreads();
  }

  #pragma unroll
  for (int j = 0; j < 4; j++) {
    const int c = tx * 4 + j;
    if (c >= N) continue;
    const float bv = bias ? bias[c] : 0.f;
    #pragma unroll
    for (int i = 0; i < 4; i++) {
      const int r = row0 + ty * 4 + i;
      O[(size_t)r * N + c] = acc[i][j] + bv;
    }
  }
}

// ---------------------------------------------------------------------------
// elementwise fp32 -> bf16
// ---------------------------------------------------------------------------
__global__ __launch_bounds__(256) void f2b_k(const float* __restrict__ in,
                                             short* __restrict__ out) {
  const int i = blockIdx.x * 256 + threadIdx.x;
  const float4 v = ((const float4*)in)[i];
  bf16x4 o;
  o[0] = f2bf(v.x); o[1] = f2bf(v.y); o[2] = f2bf(v.z); o[3] = f2bf(v.w);
  ((bf16x4*)out)[i] = o;
}

// scaled bias copy: q-part (n<1024) gets *0.125
__global__ void bscale_k(const float* __restrict__ in, float* __restrict__ out) {
  const int n = blockIdx.x * 256 + threadIdx.x;
  if (n < 3072) out[n] = in[n] * (n < 1024 ? 0.125f : 1.f);
}

// ---------------------------------------------------------------------------
// transpose + convert: W fp32 [K][N] -> Wt bf16 [N][K]; qscale: n<1024 *0.125
// ---------------------------------------------------------------------------
__global__ __launch_bounds__(256) void tconv_k(const float* __restrict__ W,
                                               short* __restrict__ Wt,
                                               int K, int N, int qscale) {
  __shared__ float tile[32][33];
  const int k0 = blockIdx.y * 32, n0 = blockIdx.x * 32;
  const int tx = threadIdx.x & 31, ty = threadIdx.x >> 5;
  #pragma unroll
  for (int i = 0; i < 4; i++)
    tile[ty * 4 + i][tx] = W[(size_t)(k0 + ty * 4 + i) * N + n0 + tx];
  __syncthreads();
  #pragma unroll
  for (int i = 0; i < 4; i++) {
    const int n = n0 + ty * 4 + i;
    const float s = (qscale && n < 1024) ? 0.125f : 1.f;
    Wt[(size_t)n * K + k0 + tx] = f2bf(tile[tx][ty * 4 + i] * s);
  }
}

// ---------------------------------------------------------------------------
// bf16 MFMA GEMM: C[M,N] = A[M,K](bf16) @ Wt[N,K]^T (bf16) + bias
// ---------------------------------------------------------------------------
template<bool BF16_OUT>
__global__ __launch_bounds__(256) void gemm_bf16_k(
    const short* __restrict__ A, const short* __restrict__ Bt,
    const float* __restrict__ bias, void* __restrict__ Cv,
    int M, int N, int K)
{
  __shared__ short As[128][40];
  __shared__ short Bs[128][40];
  const int m0 = blockIdx.y * 128, n0 = blockIdx.x * 128;
  const int tid = threadIdx.x;
  const int wave = tid >> 6, lane = tid & 63;
  const int l15 = lane & 15, lg = lane >> 4;
  const int wm = wave >> 1, wn = wave & 1;

  fx4 acc[4][4] = {};

  for (int k0 = 0; k0 < K; k0 += 32) {
    __syncthreads();
    #pragma unroll
    for (int e = tid; e < 512; e += 256) {
      const int r = e >> 2, c = e & 3;
      *(bf16x8*)&As[r][c * 8] = *(const bf16x8*)&A[(size_t)(m0 + r) * K + k0 + c * 8];
    }
    #pragma unroll
    for (int e = tid; e < 512; e += 256) {
      const int r = e >> 2, c = e & 3;
      *(bf16x8*)&Bs[r][c * 8] = *(const bf16x8*)&Bt[(size_t)(n0 + r) * K + k0 + c * 8];
    }
    __syncthreads();
    bf16x8 af[4], bf[4];
    #pragma unroll
    for (int i = 0; i < 4; i++) {
      af[i] = *(const bf16x8*)&As[wm * 64 + i * 16 + l15][8 * lg];
      bf[i] = *(const bf16x8*)&Bs[wn * 64 + i * 16 + l15][8 * lg];
    }
    __builtin_amdgcn_s_setprio(1);
    #pragma unroll
    for (int i = 0; i < 4; i++)
      #pragma unroll
      for (int j = 0; j < 4; j++)
        acc[i][j] = __builtin_amdgcn_mfma_f32_16x16x32_bf16(af[i], bf[j], acc[i][j], 0, 0, 0);
    __builtin_amdgcn_s_setprio(0);
  }

  #pragma unroll
  for (int i = 0; i < 4; i++)
    #pragma unroll
    for (int j = 0; j < 4; j++) {
      const int n = n0 + wn * 64 + j * 16 + l15;
      const float bv = bias ? bias[n] : 0.f;
      #pragma unroll
      for (int rg = 0; rg < 4; rg++) {
        const int m = m0 + wm * 64 + i * 16 + lg * 4 + rg;
        const float v = acc[i][j][rg] + bv;
        if constexpr (BF16_OUT)
          ((short*)Cv)[(size_t)m * N + n] = f2bf(v);
        else
          ((float*)Cv)[(size_t)m * N + n] = v;
      }
    }
}

// ---------------------------------------------------------------------------
// Pluecker lines
// ---------------------------------------------------------------------------
__device__ __forceinline__ void exterior6(const float a[4], const float c[4], float L[6]) {
  L[0] = a[0]*c[1] - a[1]*c[0];
  L[1] = a[0]*c[2] - a[2]*c[0];
  L[2] = a[0]*c[3] - a[3]*c[0];
  L[3] = a[1]*c[2] - a[2]*c[1];
  L[4] = a[1]*c[3] - a[3]*c[1];
  L[5] = a[2]*c[3] - a[3]*c[2];
}

__global__ void lines_k(const float* __restrict__ w1f, const float* __restrict__ w2f,
                        const float* __restrict__ r1f, const float* __restrict__ r2f,
                        const float* __restrict__ incs,
                        float* __restrict__ JW, float* __restrict__ RL)
{
  const int idx = blockIdx.x * 256 + threadIdx.x;
  if (idx >= Bc * Tc * Hc) return;
  const int h = idx & 15;
  const int t = (idx >> 4) & (Tc - 1);
  const int b = idx >> 15;
  const size_t row = (size_t)b * Tc + t;
  const size_t lrow = ((size_t)(b * Hc + h) * Tc + t) * 6;

  float a[4] = {0.f, 0.f, 0.f, 0.f};
  float c[4];
  {
    const float4 c4 = *(const float4*)&w2f[row * 64 + h * 4];
    c[0] = c4.x; c[1] = c4.y; c[2] = c4.z; c[3] = c4.w;
    if (t > 0) {
      const float4 a4 = *(const float4*)&w1f[(row - 1) * 64 + h * 4];
      a[0] = a4.x; a[1] = a4.y; a[2] = a4.z; a[3] = a4.w;
    }
  }
  float L[6];
  exterior6(a, c, L);
  float n = sqrtf(L[0]*L[0] + L[1]*L[1] + L[2]*L[2] + L[3]*L[3] + L[4]*L[4] + L[5]*L[5]);
  float inv = 1.f / fmaxf(n, 1e-12f);
  const float s = incs[h];
  JW[lrow + 0] =  L[5] * inv * s;
  JW[lrow + 1] = -L[4] * inv * s;
  JW[lrow + 2] =  L[3] * inv * s;
  JW[lrow + 3] =  L[2] * inv * s;
  JW[lrow + 4] = -L[1] * inv * s;
  JW[lrow + 5] =  L[0] * inv * s;

  {
    const float4 a4 = *(const float4*)&r1f[row * 64 + h * 4];
    const float4 c4 = *(const float4*)&r2f[row * 64 + h * 4];
    a[0] = a4.x; a[1] = a4.y; a[2] = a4.z; a[3] = a4.w;
    c[0] = c4.x; c[1] = c4.y; c[2] = c4.z; c[3] = c4.w;
  }
  exterior6(a, c, L);
  n = sqrtf(L[0]*L[0] + L[1]*L[1] + L[2]*L[2] + L[3]*L[3] + L[4]*L[4] + L[5]*L[5]);
  inv = 1.f / fmaxf(n, 1e-12f);
  #pragma unroll
  for (int i = 0; i < 6; i++) RL[lrow + i] = L[i] * inv;
}

__global__ void gate_k(const float* __restrict__ glin, float* __restrict__ gate) {
  const int idx = blockIdx.x * 256 + threadIdx.x;
  if (idx >= Mc) return;
  float ssum = 0.f;
  #pragma unroll
  for (int h = 0; h < 16; h++) {
    const float v = glin[(size_t)idx * 16 + h];
    ssum += 1.f / (1.f + __expf(-v));
  }
  gate[idx] = ssum * (1.f / 16.f);
}

// ---------------------------------------------------------------------------
// Dual flash attention, MFMA bf16, static softmax (logits provably bounded).
// One block per (bh, q-tile). 1024 blocks, XCD-clustered: all 32 q-tiles of a
// bh land on one XCD so its K/V/G panels (768 KB) stay L2-resident. Big
// q-tiles dispatched first within each XCD group.
// ---------------------------------------------------------------------------
__global__ __launch_bounds__(256) void attn2_k(
    const short* __restrict__ qkvb,  // (4096, 3072) bf16, q pre-scaled by 1/8
    const short* __restrict__ geovb, // (4096, 1024) bf16
    const float* __restrict__ RL,    // (B*H, T, 6)
    const float* __restrict__ JW,    // (B*H, T, 6), inc_scale folded
    const float* __restrict__ gate,  // (4096)
    short* __restrict__ combb)       // (4096, 1024) bf16
{
  const int orig = blockIdx.x;        // 0..1023
  const int xcd  = orig & 7;
  const int idx  = orig >> 3;         // 0..127
  const int qt   = 31 - (idx & 31);   // big tiles first
  const int bh   = xcd + 8 * (idx >> 5);   // 0..31, clustered per XCD
  const int b = bh >> 4, h = bh & 15;
  const int q0 = qt * QB;
  const int tid = threadIdx.x;
  const int wave = tid >> 6;
  const int lane = tid & 63;
  const int l15 = lane & 15;
  const int lg  = lane >> 4;          // 0..3

  __shared__ short Qs[QB][64];        // chunk-XOR swizzled (8 chunks)
  __shared__ short Ks[KB][64];        // chunk-XOR swizzled
  __shared__ short Vt[64][40];        // V^T, k-chunk XOR swizzled (4 chunks)
  __shared__ short Gt[64][40];        // geoV^T, same swizzle
  __shared__ short JWs[KB][40];       // cols 0..5 data, rest zero
  __shared__ short RLs[QB][40];
  __shared__ short Ps[4][16][40];     // per-wave P (std) [q][k]
  __shared__ short Pg[4][16][40];     // per-wave P (geo)

  for (int e = tid; e < KB * 40; e += 256) (&JWs[0][0])[e] = 0;
  for (int e = tid; e < QB * 40; e += 256) (&RLs[0][0])[e] = 0;
  __syncthreads();

  for (int e = tid; e < QB * 8; e += 256) {
    const int r = e >> 3, c = e & 7;
    bf16x8 v = *(const bf16x8*)&qkvb[(size_t)(b * Tc + q0 + r) * 3072 + h * 64 + c * 8];
    *(bf16x8*)&Qs[r][8 * (c ^ (r & 7))] = v;
  }
  for (int e = tid; e < QB * 6; e += 256) {
    const int r = e / 6, i = e % 6;
    RLs[r][i] = f2bf(RL[((size_t)bh * Tc + q0 + r) * 6 + i]);
  }
  __syncthreads();

  const int qrow = wave * 16 + l15;
  const bf16x8 qf0 = *(const bf16x8*)&Qs[qrow][8 * ((0 + lg) ^ (qrow & 7))];
  const bf16x8 qf1 = *(const bf16x8*)&Qs[qrow][8 * ((4 + lg) ^ (qrow & 7))];
  const bf16x8 rlf = *(const bf16x8*)&RLs[qrow][8 * lg];

  fx4 accS[4] = {}, accG[4] = {};
  float lpS[4] = {0.f, 0.f, 0.f, 0.f};
  float lpG[4] = {0.f, 0.f, 0.f, 0.f};

  const int nkt = 2 * qt + 2;
  const int qhi = q0 + wave * 16 + 15;

  for (int kt = 0; kt < nkt; kt++) {
    const int k0 = kt * KB;
    __syncthreads();
    // stage K (swizzled)
    {
      const int r = tid >> 3, c = tid & 7;
      bf16x8 v = *(const bf16x8*)&qkvb[(size_t)(b * Tc + k0 + r) * 3072 + 1024 + h * 64 + c * 8];
      *(bf16x8*)&Ks[r][8 * (c ^ (r & 7))] = v;
    }
    // stage Vt / Gt transposed with k-chunk XOR swizzle
    {
      const int k = tid >> 3, dg = (tid & 7) * 8;
      bf16x8 v = *(const bf16x8*)&qkvb[(size_t)(b * Tc + k0 + k) * 3072 + 2048 + h * 64 + dg];
      bf16x8 g2 = *(const bf16x8*)&geovb[(size_t)(b * Tc + k0 + k) * 1024 + h * 64 + dg];
      const int kc = k >> 3, kl = k & 7;
      #pragma unroll
      for (int j = 0; j < 8; j++) {
        const int d = dg + j;
        const int col = ((kc ^ ((d >> 3) & 3)) << 3) | kl;
        Vt[d][col] = v[j];
        Gt[d][col] = g2[j];
      }
    }
    if (tid < KB * 6) {
      const int r = tid / 6, i = tid % 6;
      JWs[r][i] = f2bf(JW[((size_t)bh * Tc + k0 + r) * 6 + i]);
    }
    __syncthreads();

    if (k0 <= qhi) {
      // ---- scores via MFMA ----
      fx4 sS[2], sG[2];
      __builtin_amdgcn_s_setprio(1);
      #pragma unroll
      for (int ks = 0; ks < 2; ks++) {
        const int krow = ks * 16 + l15;
        const bf16x8 kf0 = *(const bf16x8*)&Ks[krow][8 * ((0 + lg) ^ (krow & 7))];
        const bf16x8 kf1 = *(const bf16x8*)&Ks[krow][8 * ((4 + lg) ^ (krow & 7))];
        fx4 z = {0.f, 0.f, 0.f, 0.f};
        fx4 s = __builtin_amdgcn_mfma_f32_16x16x32_bf16(qf0, kf0, z, 0, 0, 0);
        s = __builtin_amdgcn_mfma_f32_16x16x32_bf16(qf1, kf1, s, 0, 0, 0);
        sS[ks] = s;
        const bf16x8 jwf = *(const bf16x8*)&JWs[krow][8 * lg];
        sG[ks] = __builtin_amdgcn_mfma_f32_16x16x32_bf16(rlf, jwf, z, 0, 0, 0);
      }
      __builtin_amdgcn_s_setprio(0);

      // ---- causal mask (diagonal-straddling tiles only) ----
      if (k0 + KB - 1 > q0 + wave * 16) {
        #pragma unroll
        for (int ks = 0; ks < 2; ks++) {
          const int kg = k0 + ks * 16 + l15;
          #pragma unroll
          for (int r = 0; r < 4; r++) {
            const int qg = q0 + wave * 16 + lg * 4 + r;
            if (kg > qg) { sS[ks][r] = -1e30f; sG[ks][r] = -1e30f; }
          }
        }
      }

      // ---- static softmax: p = exp(s), partial sums per lane ----
      #pragma unroll
      for (int r = 0; r < 4; r++) {
        const int ql = lg * 4 + r;
        const float p0 = __expf(sS[0][r]);
        const float p1 = __expf(sS[1][r]);
        lpS[r] += p0 + p1;
        Ps[wave][ql][l15]      = f2bf(p0);
        Ps[wave][ql][16 + l15] = f2bf(p1);
        const float g0 = __expf(sG[0][r]);
        const float g1 = __expf(sG[1][r]);
        lpG[r] += g0 + g1;
        Pg[wave][ql][l15]      = f2bf(g0);
        Pg[wave][ql][16 + l15] = f2bf(g1);
      }

      // ---- PV via MFMA ----
      const bf16x8 pa  = *(const bf16x8*)&Ps[wave][l15][8 * lg];
      const bf16x8 pga = *(const bf16x8*)&Pg[wave][l15][8 * lg];
      __builtin_amdgcn_s_setprio(1);
      #pragma unroll
      for (int dt = 0; dt < 4; dt++) {
        const int dV = dt * 16 + l15;
        const int swz = 8 * (lg ^ ((dV >> 3) & 3));
        const bf16x8 vf = *(const bf16x8*)&Vt[dV][swz];
        accS[dt] = __builtin_amdgcn_mfma_f32_16x16x32_bf16(pa, vf, accS[dt], 0, 0, 0);
        const bf16x8 gf = *(const bf16x8*)&Gt[dV][swz];
        accG[dt] = __builtin_amdgcn_mfma_f32_16x16x32_bf16(pga, gf, accG[dt], 0, 0, 0);
      }
      __builtin_amdgcn_s_setprio(0);
    }
  }

  // ---- epilogue: one reduction per row, normalize + gate combine ----
  #pragma unroll
  for (int r = 0; r < 4; r++) {
    float ls = lpS[r];
    ls += __shfl_xor(ls, 1); ls += __shfl_xor(ls, 2);
    ls += __shfl_xor(ls, 4); ls += __shfl_xor(ls, 8);
    float lgeo = lpG[r];
    lgeo += __shfl_xor(lgeo, 1); lgeo += __shfl_xor(lgeo, 2);
    lgeo += __shfl_xor(lgeo, 4); lgeo += __shfl_xor(lgeo, 8);
    const int qg = q0 + wave * 16 + lg * 4 + r;
    const float gt = gate[(size_t)b * Tc + qg];
    const float invS = (1.f - gt) / ls;
    const float invG = gt / lgeo;
    #pragma unroll
    for (int dt = 0; dt < 4; dt++) {
      const float o = accS[dt][r] * invS + accG[dt][r] * invG;
      combb[(size_t)(b * Tc + qg) * 1024 + h * 64 + dt * 16 + l15] = f2bf(o);
    }
  }
}

// ---------------------------------------------------------------------------
extern "C" void kernel_launch(void* const* d_in, const int* in_sizes, int n_in,
                              void* d_out, int out_size, void* d_ws, size_t ws_size,
                              hipStream_t stream) {
  (void)in_sizes; (void)n_in; (void)out_size; (void)ws_size;
  const float* x     = (const float*)d_in[0];
  const float* qkv_w = (const float*)d_in[1];
  const float* qkv_b = (const float*)d_in[2];
  const float* w1w   = (const float*)d_in[3];
  const float* w2w   = (const float*)d_in[4];
  const float* w1r   = (const float*)d_in[5];
  const float* w2r   = (const float*)d_in[6];
  const float* geow  = (const float*)d_in[7];
  const float* geob  = (const float*)d_in[8];
  const float* gatew = (const float*)d_in[9];
  const float* gateb = (const float*)d_in[10];
  const float* incs  = (const float*)d_in[11];
  const float* outw  = (const float*)d_in[12];
  const float* outb  = (const float*)d_in[13];
  float* out = (float*)d_out;

  char* p = (char*)d_ws;
  short* xb    = (short*)p;               p += (size_t)4096 * 1024 * 2;
  short* qkvb  = (short*)p;               p += (size_t)4096 * 3072 * 2;
  short* geovb = (short*)p;               p += (size_t)4096 * 1024 * 2;
  short* combb = (short*)p;               p += (size_t)4096 * 1024 * 2;
  short* wtqkv = (short*)p;               p += (size_t)3072 * 1024 * 2;
  short* wtgeo = (short*)p;               p += (size_t)1024 * 1024 * 2;
  short* wtout = (short*)p;               p += (size_t)1024 * 1024 * 2;
  float* w1f   = (float*)p;               p += (size_t)4096 * 64 * 4;
  float* w2f   = (float*)p;               p += (size_t)4096 * 64 * 4;
  float* r1f   = (float*)p;               p += (size_t)4096 * 64 * 4;
  float* r2f   = (float*)p;               p += (size_t)4096 * 64 * 4;
  float* JW    = (float*)p;               p += (size_t)393216 * 4;
  float* RLp   = (float*)p;               p += (size_t)393216 * 4;
  float* glin  = (float*)p;               p += (size_t)4096 * 16 * 4;
  float* gatev = (float*)p;               p += (size_t)4096 * 4;
  float* qkvbs = (float*)p;               p += (size_t)3072 * 4;

  const dim3 blk(256);

  f2b_k<<<dim3(4096), blk, 0, stream>>>(x, xb);
  bscale_k<<<dim3(12), blk, 0, stream>>>(qkv_b, qkvbs);
  tconv_k<<<dim3(96, 32), blk, 0, stream>>>(qkv_w, wtqkv, 1024, 3072, 1);
  tconv_k<<<dim3(32, 32), blk, 0, stream>>>(geow, wtgeo, 1024, 1024, 0);
  tconv_k<<<dim3(32, 32), blk, 0, stream>>>(outw, wtout, 1024, 1024, 0);

  gemm_bf16_k<true><<<dim3(24, 32), blk, 0, stream>>>(xb, wtqkv, qkvbs, qkvb, 4096, 3072, 1024);
  gemm_bf16_k<true><<<dim3(8, 32), blk, 0, stream>>>(xb, wtgeo, geob, geovb, 4096, 1024, 1024);

  gemm_small_k<<<dim3(5, 64), blk, 0, stream>>>(x, w1w, w2w, w1r, w2r, gatew, gateb,
                                                w1f, w2f, r1f, r2f, glin);

  lines_k<<<dim3((Bc * Tc * Hc + 255) / 256), blk, 0, stream>>>(w1f, w2f, r1f, r2f, incs, JW, RLp);
  gate_k<<<dim3((Mc + 255) / 256), blk, 0, stream>>>(glin, gatev);

  attn2_k<<<dim3(1024), blk, 0, stream>>>(qkvb, geovb, RLp, JW, gatev, combb);

  gemm_bf16_k<false><<<dim3(8, 32), blk, 0, stream>>>(combb, wtout, outb, (void*)out, 4096, 1024, 1024);
}

// Round 6
// 323.756 us; speedup vs baseline: 1.1628x; 1.1628x over previous
//
#include <hip/hip_runtime.h>
#include <hip/hip_bf16.h>

#define Bc 2
#define Tc 2048
#define Dc 1024
#define Hc 16
#define Mc (Bc*Tc)   // 4096
#define QB 64
#define KB 32

typedef __attribute__((ext_vector_type(8))) short bf16x8;
typedef __attribute__((ext_vector_type(4))) short bf16x4;
typedef __attribute__((ext_vector_type(4))) float fx4;

__device__ __forceinline__ short f2bf(float f) {
  __hip_bfloat16 h = __float2bfloat16(f);
  return *reinterpret_cast<short*>(&h);
}

#define MFMA(a, b, c) __builtin_amdgcn_mfma_f32_16x16x32_bf16((a), (b), (c), 0, 0, 0)

// ---------------------------------------------------------------------------
// merged small fp32 GEMMs: z=0..3 -> N=64 (w1w,w2w,w1r,w2r), z=4 -> N=16 gate
// ---------------------------------------------------------------------------
__global__ __launch_bounds__(256) void gemm_small_k(
    const float* __restrict__ A,
    const float* __restrict__ W0, const float* __restrict__ W1,
    const float* __restrict__ W2, const float* __restrict__ W3,
    const float* __restrict__ W4, const float* __restrict__ b4,
    float* __restrict__ O0, float* __restrict__ O1,
    float* __restrict__ O2, float* __restrict__ O3, float* __restrict__ O4)
{
  const int z = blockIdx.x;
  const float* W; float* O; int N; const float* bias = nullptr;
  if      (z == 0) { W = W0; O = O0; N = 64; }
  else if (z == 1) { W = W1; O = O1; N = 64; }
  else if (z == 2) { W = W2; O = O2; N = 64; }
  else if (z == 3) { W = W3; O = O3; N = 64; }
  else             { W = W4; O = O4; N = 16; bias = b4; }

  __shared__ float As[16][68];
  __shared__ float Ws[16][68];
  const int row0 = blockIdx.y * 64;
  const int tid  = threadIdx.x;
  const int tx = tid & 15, ty = tid >> 4;
  const int K = 1024;

  float acc[4][4] = {};

  for (int k0 = 0; k0 < K; k0 += 16) {
    {
      const int r  = tid >> 2;
      const int kc = (tid & 3) * 4;
      const float4 a4 = *(const float4*)&A[(size_t)(row0 + r) * K + k0 + kc];
      As[kc + 0][r] = a4.x; As[kc + 1][r] = a4.y;
      As[kc + 2][r] = a4.z; As[kc + 3][r] = a4.w;
    }
    {
      const int kr = tid >> 4;
      const int c  = (tid & 15) * 4;
      float4 w4 = make_float4(0.f, 0.f, 0.f, 0.f);
      if (c + 3 < N) {
        w4 = *(const float4*)&W[(size_t)(k0 + kr) * N + c];
      } else if (c < N) {
        w4.x = W[(size_t)(k0 + kr) * N + c];
        if (c + 1 < N) w4.y = W[(size_t)(k0 + kr) * N + c + 1];
        if (c + 2 < N) w4.z = W[(size_t)(k0 + kr) * N + c + 2];
      }
      *(float4*)&Ws[kr][c] = w4;
    }
    __syncthreads();
    #pragma unroll
    for (int kk = 0; kk < 16; kk++) {
      const float4 a4 = *(const float4*)&As[kk][ty * 4];
      const float4 w4 = *(const float4*)&Ws[kk][tx * 4];
      const float a[4] = {a4.x, a4.y, a4.z, a4.w};
      const float w[4] = {w4.x, w4.y, w4.z, w4.w};
      #pragma unroll
      for (int i = 0; i < 4; i++)
        #pragma unroll
        for (int j = 0; j < 4; j++)
          acc[i][j] = fmaf(a[i], w[j], acc[i][j]);
    }
    __syncthreads();
  }

  #pragma unroll
  for (int j = 0; j < 4; j++) {
    const int c = tx * 4 + j;
    if (c >= N) continue;
    const float bv = bias ? bias[c] : 0.f;
    #pragma unroll
    for (int i = 0; i < 4; i++) {
      const int r = row0 + ty * 4 + i;
      O[(size_t)r * N + c] = acc[i][j] + bv;
    }
  }
}

// ---------------------------------------------------------------------------
__global__ __launch_bounds__(256) void f2b_k(const float* __restrict__ in,
                                             short* __restrict__ out) {
  const int i = blockIdx.x * 256 + threadIdx.x;
  const float4 v = ((const float4*)in)[i];
  bf16x4 o;
  o[0] = f2bf(v.x); o[1] = f2bf(v.y); o[2] = f2bf(v.z); o[3] = f2bf(v.w);
  ((bf16x4*)out)[i] = o;
}

__global__ void bscale_k(const float* __restrict__ in, float* __restrict__ out) {
  const int n = blockIdx.x * 256 + threadIdx.x;
  if (n < 3072) out[n] = in[n] * (n < 1024 ? 0.125f : 1.f);
}

// ---------------------------------------------------------------------------
__global__ __launch_bounds__(256) void tconv_k(const float* __restrict__ W,
                                               short* __restrict__ Wt,
                                               int K, int N, int qscale) {
  __shared__ float tile[32][33];
  const int k0 = blockIdx.y * 32, n0 = blockIdx.x * 32;
  const int tx = threadIdx.x & 31, ty = threadIdx.x >> 5;
  #pragma unroll
  for (int i = 0; i < 4; i++)
    tile[ty * 4 + i][tx] = W[(size_t)(k0 + ty * 4 + i) * N + n0 + tx];
  __syncthreads();
  #pragma unroll
  for (int i = 0; i < 4; i++) {
    const int n = n0 + ty * 4 + i;
    const float s = (qscale && n < 1024) ? 0.125f : 1.f;
    Wt[(size_t)n * K + k0 + tx] = f2bf(tile[tx][ty * 4 + i] * s);
  }
}

// ---------------------------------------------------------------------------
template<bool BF16_OUT>
__global__ __launch_bounds__(256) void gemm_bf16_k(
    const short* __restrict__ A, const short* __restrict__ Bt,
    const float* __restrict__ bias, void* __restrict__ Cv,
    int M, int N, int K)
{
  __shared__ short As[128][40];
  __shared__ short Bs[128][40];
  const int m0 = blockIdx.y * 128, n0 = blockIdx.x * 128;
  const int tid = threadIdx.x;
  const int wave = tid >> 6, lane = tid & 63;
  const int l15 = lane & 15, lg = lane >> 4;
  const int wm = wave >> 1, wn = wave & 1;

  fx4 acc[4][4] = {};

  for (int k0 = 0; k0 < K; k0 += 32) {
    __syncthreads();
    #pragma unroll
    for (int e = tid; e < 512; e += 256) {
      const int r = e >> 2, c = e & 3;
      *(bf16x8*)&As[r][c * 8] = *(const bf16x8*)&A[(size_t)(m0 + r) * K + k0 + c * 8];
    }
    #pragma unroll
    for (int e = tid; e < 512; e += 256) {
      const int r = e >> 2, c = e & 3;
      *(bf16x8*)&Bs[r][c * 8] = *(const bf16x8*)&Bt[(size_t)(n0 + r) * K + k0 + c * 8];
    }
    __syncthreads();
    bf16x8 af[4], bf[4];
    #pragma unroll
    for (int i = 0; i < 4; i++) {
      af[i] = *(const bf16x8*)&As[wm * 64 + i * 16 + l15][8 * lg];
      bf[i] = *(const bf16x8*)&Bs[wn * 64 + i * 16 + l15][8 * lg];
    }
    __builtin_amdgcn_s_setprio(1);
    #pragma unroll
    for (int i = 0; i < 4; i++)
      #pragma unroll
      for (int j = 0; j < 4; j++)
        acc[i][j] = MFMA(af[i], bf[j], acc[i][j]);
    __builtin_amdgcn_s_setprio(0);
  }

  #pragma unroll
  for (int i = 0; i < 4; i++)
    #pragma unroll
    for (int j = 0; j < 4; j++) {
      const int n = n0 + wn * 64 + j * 16 + l15;
      const float bv = bias ? bias[n] : 0.f;
      #pragma unroll
      for (int rg = 0; rg < 4; rg++) {
        const int m = m0 + wm * 64 + i * 16 + lg * 4 + rg;
        const float v = acc[i][j][rg] + bv;
        if constexpr (BF16_OUT)
          ((short*)Cv)[(size_t)m * N + n] = f2bf(v);
        else
          ((float*)Cv)[(size_t)m * N + n] = v;
      }
    }
}

// ---------------------------------------------------------------------------
// Pluecker lines -> bf16 padded-8 rows: RLb[bh][t][8], JWb[bh][t][8]
// ---------------------------------------------------------------------------
__device__ __forceinline__ void exterior6(const float a[4], const float c[4], float L[6]) {
  L[0] = a[0]*c[1] - a[1]*c[0];
  L[1] = a[0]*c[2] - a[2]*c[0];
  L[2] = a[0]*c[3] - a[3]*c[0];
  L[3] = a[1]*c[2] - a[2]*c[1];
  L[4] = a[1]*c[3] - a[3]*c[1];
  L[5] = a[2]*c[3] - a[3]*c[2];
}

__global__ void lines_k(const float* __restrict__ w1f, const float* __restrict__ w2f,
                        const float* __restrict__ r1f, const float* __restrict__ r2f,
                        const float* __restrict__ incs,
                        short* __restrict__ JWb, short* __restrict__ RLb)
{
  const int idx = blockIdx.x * 256 + threadIdx.x;
  if (idx >= Bc * Tc * Hc) return;
  const int h = idx & 15;
  const int t = (idx >> 4) & (Tc - 1);
  const int b = idx >> 15;
  const size_t row = (size_t)b * Tc + t;
  const size_t lrow = ((size_t)(b * Hc + h) * Tc + t) * 8;

  float a[4] = {0.f, 0.f, 0.f, 0.f};
  float c[4];
  {
    const float4 c4 = *(const float4*)&w2f[row * 64 + h * 4];
    c[0] = c4.x; c[1] = c4.y; c[2] = c4.z; c[3] = c4.w;
    if (t > 0) {
      const float4 a4 = *(const float4*)&w1f[(row - 1) * 64 + h * 4];
      a[0] = a4.x; a[1] = a4.y; a[2] = a4.z; a[3] = a4.w;
    }
  }
  float L[6];
  exterior6(a, c, L);
  float n = sqrtf(L[0]*L[0] + L[1]*L[1] + L[2]*L[2] + L[3]*L[3] + L[4]*L[4] + L[5]*L[5]);
  float inv = 1.f / fmaxf(n, 1e-12f);
  const float s = incs[h];
  bf16x8 jw;
  jw[0] = f2bf( L[5] * inv * s);
  jw[1] = f2bf(-L[4] * inv * s);
  jw[2] = f2bf( L[3] * inv * s);
  jw[3] = f2bf( L[2] * inv * s);
  jw[4] = f2bf(-L[1] * inv * s);
  jw[5] = f2bf( L[0] * inv * s);
  jw[6] = 0; jw[7] = 0;
  *(bf16x8*)&JWb[lrow] = jw;

  {
    const float4 a4 = *(const float4*)&r1f[row * 64 + h * 4];
    const float4 c4 = *(const float4*)&r2f[row * 64 + h * 4];
    a[0] = a4.x; a[1] = a4.y; a[2] = a4.z; a[3] = a4.w;
    c[0] = c4.x; c[1] = c4.y; c[2] = c4.z; c[3] = c4.w;
  }
  exterior6(a, c, L);
  n = sqrtf(L[0]*L[0] + L[1]*L[1] + L[2]*L[2] + L[3]*L[3] + L[4]*L[4] + L[5]*L[5]);
  inv = 1.f / fmaxf(n, 1e-12f);
  bf16x8 rl;
  #pragma unroll
  for (int i = 0; i < 6; i++) rl[i] = f2bf(L[i] * inv);
  rl[6] = 0; rl[7] = 0;
  *(bf16x8*)&RLb[lrow] = rl;
}

__global__ void gate_k(const float* __restrict__ glin, float* __restrict__ gate) {
  const int idx = blockIdx.x * 256 + threadIdx.x;
  if (idx >= Mc) return;
  float ssum = 0.f;
  #pragma unroll
  for (int h = 0; h < 16; h++) {
    const float v = glin[(size_t)idx * 16 + h];
    ssum += 1.f / (1.f + __expf(-v));
  }
  gate[idx] = ssum * (1.f / 16.f);
}

// ---------------------------------------------------------------------------
// Dual flash attention v3: paired q-tiles (uniform 66 k-tiles/block), XCD
// clustering, 1 barrier/iter, double-buffered V/G LDS staging, K/Q/RL/JW
// direct global->register (prefetched one tile ahead). Static softmax.
// ---------------------------------------------------------------------------
#define LOADK(K0, a0, a1, b0, b1) { \
  const size_t rb0 = (size_t)(b * Tc + (K0) + l15) * 3072 + 1024 + h * 64; \
  const size_t rb1 = rb0 + (size_t)16 * 3072; \
  a0 = *(const bf16x8*)&qkvb[rb0 + lg * 8]; \
  a1 = *(const bf16x8*)&qkvb[rb0 + 32 + lg * 8]; \
  b0 = *(const bf16x8*)&qkvb[rb1 + lg * 8]; \
  b1 = *(const bf16x8*)&qkvb[rb1 + 32 + lg * 8]; }

#define LOADJW(K0, j0, j1) { \
  j0 = z8; j1 = z8; \
  if (lg == 0) { \
    j0 = *(const bf16x8*)&JWb[(size_t)(bh * Tc + (K0) + l15) * 8]; \
    j1 = *(const bf16x8*)&JWb[(size_t)(bh * Tc + (K0) + 16 + l15) * 8]; \
  } }

#define LOADVG(K0, vr, gr) { \
  vr = *(const bf16x8*)&qkvb[(size_t)(b * Tc + (K0) + kk) * 3072 + 2048 + h * 64 + dg]; \
  gr = *(const bf16x8*)&geovb[(size_t)(b * Tc + (K0) + kk) * 1024 + h * 64 + dg]; }

#define STAGEVG(CUR, vr, gr) { \
  _Pragma("unroll") for (int j = 0; j < 8; j++) { \
    const int d = dg + j; \
    const int col = ((kc2 ^ ((d >> 3) & 3)) << 3) | kl2; \
    Vt[CUR][d][col] = vr[j]; Gt[CUR][d][col] = gr[j]; \
  } }

#define COMPUTE(K0, CUR, ka0, ka1, kb0, kb1, jw0, jw1) \
  if ((K0) <= qhi) { \
    fx4 z = {0.f, 0.f, 0.f, 0.f}; \
    fx4 sS0, sS1, sG0, sG1; \
    __builtin_amdgcn_s_setprio(1); \
    sS0 = MFMA(qf0, ka0, z); sS0 = MFMA(qf1, ka1, sS0); \
    sS1 = MFMA(qf0, kb0, z); sS1 = MFMA(qf1, kb1, sS1); \
    sG0 = MFMA(rlf, jw0, z); sG1 = MFMA(rlf, jw1, z); \
    __builtin_amdgcn_s_setprio(0); \
    if ((K0) + KB - 1 > q0 + wave * 16) { \
      const int kg0 = (K0) + l15, kg1 = (K0) + 16 + l15; \
      _Pragma("unroll") for (int r = 0; r < 4; r++) { \
        const int qg = q0 + wave * 16 + lg * 4 + r; \
        if (kg0 > qg) { sS0[r] = -1e30f; sG0[r] = -1e30f; } \
        if (kg1 > qg) { sS1[r] = -1e30f; sG1[r] = -1e30f; } \
      } } \
    _Pragma("unroll") for (int r = 0; r < 4; r++) { \
      const int ql = lg * 4 + r; \
      const float p0 = __expf(sS0[r]); const float p1 = __expf(sS1[r]); \
      lpS[r] += p0 + p1; \
      Ps[wave][ql][l15] = f2bf(p0); Ps[wave][ql][16 + l15] = f2bf(p1); \
      const float g0 = __expf(sG0[r]); const float g1 = __expf(sG1[r]); \
      lpG[r] += g0 + g1; \
      Pg[wave][ql][l15] = f2bf(g0); Pg[wave][ql][16 + l15] = f2bf(g1); \
    } \
    const bf16x8 pa  = *(const bf16x8*)&Ps[wave][l15][8 * lg]; \
    const bf16x8 pga = *(const bf16x8*)&Pg[wave][l15][8 * lg]; \
    __builtin_amdgcn_s_setprio(1); \
    _Pragma("unroll") for (int dt = 0; dt < 4; dt++) { \
      const int dV = dt * 16 + l15; \
      const int swz = 8 * (lg ^ ((dV >> 3) & 3)); \
      accS[dt] = MFMA(pa,  *(const bf16x8*)&Vt[CUR][dV][swz], accS[dt]); \
      accG[dt] = MFMA(pga, *(const bf16x8*)&Gt[CUR][dV][swz], accG[dt]); \
    } \
    __builtin_amdgcn_s_setprio(0); \
  }

__global__ __launch_bounds__(256) void attn3_k(
    const short* __restrict__ qkvb,  // (4096, 3072) bf16, q pre-scaled by 1/8
    const short* __restrict__ geovb, // (4096, 1024) bf16
    const short* __restrict__ RLb,   // (B*H, T, 8) bf16
    const short* __restrict__ JWb,   // (B*H, T, 8) bf16, inc_scale folded
    const float* __restrict__ gate,  // (4096)
    short* __restrict__ combb)       // (4096, 1024) bf16
{
  const int orig = blockIdx.x;        // 0..511
  const int xcd  = orig & 7;
  const int idx  = orig >> 3;         // 0..63
  const int pairIdx = idx & 15;
  const int bh   = xcd + 8 * (idx >> 4);  // 4 bh per XCD
  const int b = bh >> 4, h = bh & 15;
  const int tid = threadIdx.x;
  const int wave = tid >> 6;
  const int lane = tid & 63;
  const int l15 = lane & 15;
  const int lg  = lane >> 4;
  const int kk  = tid >> 3;           // staging k row 0..31
  const int dg  = (tid & 7) * 8;      // staging d group
  const int kc2 = kk >> 3, kl2 = kk & 7;

  __shared__ short Vt[2][64][40];
  __shared__ short Gt[2][64][40];
  __shared__ short Ps[4][16][40];
  __shared__ short Pg[4][16][40];

  const bf16x8 z8 = {0, 0, 0, 0, 0, 0, 0, 0};

  for (int half = 0; half < 2; half++) {
    const int qt = half ? (31 - pairIdx) : pairIdx;
    const int q0 = qt * QB;
    const int nkt = 2 * qt + 2;       // always even
    const int qrow = wave * 16 + l15;
    const int qhi = q0 + wave * 16 + 15;

    const size_t qrb = (size_t)(b * Tc + q0 + qrow) * 3072 + h * 64;
    const bf16x8 qf0 = *(const bf16x8*)&qkvb[qrb + lg * 8];
    const bf16x8 qf1 = *(const bf16x8*)&qkvb[qrb + 32 + lg * 8];
    bf16x8 rlf = z8;
    if (lg == 0) rlf = *(const bf16x8*)&RLb[(size_t)(bh * Tc + q0 + qrow) * 8];

    fx4 accS[4] = {}, accG[4] = {};
    float lpS[4] = {0.f, 0.f, 0.f, 0.f};
    float lpG[4] = {0.f, 0.f, 0.f, 0.f};

    // prologue: tile 0 into set A
    bf16x8 kA0a, kA1a, kB0a, kB1a, jw0a, jw1a, vrA, grA;
    bf16x8 kA0b, kA1b, kB0b, kB1b, jw0b, jw1b, vrB, grB;
    LOADK(0, kA0a, kA1a, kB0a, kB1a);
    LOADJW(0, jw0a, jw1a);
    LOADVG(0, vrA, grA);

    __syncthreads();   // prev half's readers done before overwriting buf0

    for (int kt = 0; kt < nkt; kt += 2) {
      const int k0a = kt * KB, k0b = k0a + KB;
      // even: stage tile kt -> buf0, prefetch tile kt+1 -> set B
      STAGEVG(0, vrA, grA);
      LOADK(k0b, kA0b, kA1b, kB0b, kB1b);
      LOADJW(k0b, jw0b, jw1b);
      LOADVG(k0b, vrB, grB);
      __syncthreads();
      COMPUTE(k0a, 0, kA0a, kA1a, kB0a, kB1a, jw0a, jw1a);
      // odd: stage tile kt+1 -> buf1, prefetch tile kt+2 -> set A
      STAGEVG(1, vrB, grB);
      if (kt + 2 < nkt) {
        LOADK(k0b + KB, kA0a, kA1a, kB0a, kB1a);
        LOADJW(k0b + KB, jw0a, jw1a);
        LOADVG(k0b + KB, vrA, grA);
      }
      __syncthreads();
      COMPUTE(k0b, 1, kA0b, kA1b, kB0b, kB1b, jw0b, jw1b);
    }

    // epilogue: one reduction per row, normalize + gate combine
    #pragma unroll
    for (int r = 0; r < 4; r++) {
      float ls = lpS[r];
      ls += __shfl_xor(ls, 1); ls += __shfl_xor(ls, 2);
      ls += __shfl_xor(ls, 4); ls += __shfl_xor(ls, 8);
      float lgeo = lpG[r];
      lgeo += __shfl_xor(lgeo, 1); lgeo += __shfl_xor(lgeo, 2);
      lgeo += __shfl_xor(lgeo, 4); lgeo += __shfl_xor(lgeo, 8);
      const int qg = q0 + wave * 16 + lg * 4 + r;
      const float gt = gate[(size_t)b * Tc + qg];
      const float invS = (1.f - gt) / ls;
      const float invG = gt / lgeo;
      #pragma unroll
      for (int dt = 0; dt < 4; dt++) {
        const float o = accS[dt][r] * invS + accG[dt][r] * invG;
        combb[(size_t)(b * Tc + qg) * 1024 + h * 64 + dt * 16 + l15] = f2bf(o);
      }
    }
  }
}

// ---------------------------------------------------------------------------
extern "C" void kernel_launch(void* const* d_in, const int* in_sizes, int n_in,
                              void* d_out, int out_size, void* d_ws, size_t ws_size,
                              hipStream_t stream) {
  (void)in_sizes; (void)n_in; (void)out_size; (void)ws_size;
  const float* x     = (const float*)d_in[0];
  const float* qkv_w = (const float*)d_in[1];
  const float* qkv_b = (const float*)d_in[2];
  const float* w1w   = (const float*)d_in[3];
  const float* w2w   = (const float*)d_in[4];
  const float* w1r   = (const float*)d_in[5];
  const float* w2r   = (const float*)d_in[6];
  const float* geow  = (const float*)d_in[7];
  const float* geob  = (const float*)d_in[8];
  const float* gatew = (const float*)d_in[9];
  const float* gateb = (const float*)d_in[10];
  const float* incs  = (const float*)d_in[11];
  const float* outw  = (const float*)d_in[12];
  const float* outb  = (const float*)d_in[13];
  float* out = (float*)d_out;

  char* p = (char*)d_ws;
  short* xb    = (short*)p;               p += (size_t)4096 * 1024 * 2;
  short* qkvb  = (short*)p;               p += (size_t)4096 * 3072 * 2;
  short* geovb = (short*)p;               p += (size_t)4096 * 1024 * 2;
  short* combb = (short*)p;               p += (size_t)4096 * 1024 * 2;
  short* wtqkv = (short*)p;               p += (size_t)3072 * 1024 * 2;
  short* wtgeo = (short*)p;               p += (size_t)1024 * 1024 * 2;
  short* wtout = (short*)p;               p += (size_t)1024 * 1024 * 2;
  short* JWb   = (short*)p;               p += (size_t)32 * 2048 * 8 * 2;
  short* RLb   = (short*)p;               p += (size_t)32 * 2048 * 8 * 2;
  float* w1f   = (float*)p;               p += (size_t)4096 * 64 * 4;
  float* w2f   = (float*)p;               p += (size_t)4096 * 64 * 4;
  float* r1f   = (float*)p;               p += (size_t)4096 * 64 * 4;
  float* r2f   = (float*)p;               p += (size_t)4096 * 64 * 4;
  float* glin  = (float*)p;               p += (size_t)4096 * 16 * 4;
  float* gatev = (float*)p;               p += (size_t)4096 * 4;
  float* qkvbs = (float*)p;               p += (size_t)3072 * 4;

  const dim3 blk(256);

  f2b_k<<<dim3(4096), blk, 0, stream>>>(x, xb);
  bscale_k<<<dim3(12), blk, 0, stream>>>(qkv_b, qkvbs);
  tconv_k<<<dim3(96, 32), blk, 0, stream>>>(qkv_w, wtqkv, 1024, 3072, 1);
  tconv_k<<<dim3(32, 32), blk, 0, stream>>>(geow, wtgeo, 1024, 1024, 0);
  tconv_k<<<dim3(32, 32), blk, 0, stream>>>(outw, wtout, 1024, 1024, 0);

  gemm_bf16_k<true><<<dim3(24, 32), blk, 0, stream>>>(xb, wtqkv, qkvbs, qkvb, 4096, 3072, 1024);
  gemm_bf16_k<true><<<dim3(8, 32), blk, 0, stream>>>(xb, wtgeo, geob, geovb, 4096, 1024, 1024);

  gemm_small_k<<<dim3(5, 64), blk, 0, stream>>>(x, w1w, w2w, w1r, w2r, gatew, gateb,
                                                w1f, w2f, r1f, r2f, glin);

  lines_k<<<dim3((Bc * Tc * Hc + 255) / 256), blk, 0, stream>>>(w1f, w2f, r1f, r2f, incs, JWb, RLb);
  gate_k<<<dim3((Mc + 255) / 256), blk, 0, stream>>>(glin, gatev);

  attn3_k<<<dim3(512), blk, 0, stream>>>(qkvb, geovb, RLb, JWb, gatev, combb);

  gemm_bf16_k<false><<<dim3(8, 32), blk, 0, stream>>>(combb, wtout, outb, (void*)out, 4096, 1024, 1024);
}

// Round 7
// 210.705 us; speedup vs baseline: 1.7867x; 1.5365x over previous
//
#include <hip/hip_runtime.h>
#include <hip/hip_bf16.h>

#define Bc 2
#define Tc 2048
#define Dc 1024
#define Hc 16
#define Mc (Bc*Tc)   // 4096
#define QB 64
#define KB 32
#define NALL 4480    // 3072 qkv | 1024 geo | 4x64 lines | 16 gate | 112 pad

typedef __attribute__((ext_vector_type(8))) short bf16x8;
typedef __attribute__((ext_vector_type(4))) short bf16x4;
typedef __attribute__((ext_vector_type(4))) float fx4;

__device__ __forceinline__ short f2bf(float f) {
  __hip_bfloat16 h = __float2bfloat16(f);
  return *reinterpret_cast<short*>(&h);
}
__device__ __forceinline__ float bf2f(short s) {
  unsigned int u = ((unsigned int)(unsigned short)s) << 16;
  float f;
  __builtin_memcpy(&f, &u, 4);
  return f;
}

#define MFMA(a, b, c) __builtin_amdgcn_mfma_f32_16x16x32_bf16((a), (b), (c), 0, 0, 0)

// async global->LDS, 16B per lane; LDS dest = wave-uniform base + lane*16
#define GLD16(G, L) __builtin_amdgcn_global_load_lds( \
    (const __attribute__((address_space(1))) unsigned int*)(G), \
    (__attribute__((address_space(3))) unsigned int*)(L), 16, 0, 0)

// ---------------------------------------------------------------------------
// fp32 -> bf16 elementwise (x)
// ---------------------------------------------------------------------------
__global__ __launch_bounds__(256) void f2b_k(const float* __restrict__ in,
                                             short* __restrict__ out) {
  const int i = blockIdx.x * 256 + threadIdx.x;
  const float4 v = ((const float4*)in)[i];
  bf16x4 o;
  o[0] = f2bf(v.x); o[1] = f2bf(v.y); o[2] = f2bf(v.z); o[3] = f2bf(v.w);
  ((bf16x4*)out)[i] = o;
}

// ---------------------------------------------------------------------------
// fused bias vector for the merged GEMM
// ---------------------------------------------------------------------------
__global__ void biasall_k(const float* __restrict__ qkv_b,
                          const float* __restrict__ geob,
                          const float* __restrict__ gateb,
                          float* __restrict__ ball) {
  const int n = blockIdx.x * 256 + threadIdx.x;
  if (n >= NALL) return;
  float v = 0.f;
  if (n < 1024)      v = qkv_b[n] * 0.125f;
  else if (n < 3072) v = qkv_b[n];
  else if (n < 4096) v = geob[n - 3072];
  else if (n >= 4352 && n < 4368) v = gateb[n - 4352];
  ball[n] = v;
}

// ---------------------------------------------------------------------------
// merged weight transpose+convert: wtall[n][k] (bf16), n in [0,4480)
// sources: qkv_w|geow|w1w|w2w|w1r|w2r|gatew (all [1024][N_i] fp32); pad=0.
// q columns (n<1024) pre-scaled by 0.125.
// ---------------------------------------------------------------------------
__global__ __launch_bounds__(256) void tconv_all_k(
    const float* __restrict__ qkv_w, const float* __restrict__ geow,
    const float* __restrict__ w1w, const float* __restrict__ w2w,
    const float* __restrict__ w1r, const float* __restrict__ w2r,
    const float* __restrict__ gatew, short* __restrict__ wtall)
{
  __shared__ float tile[32][33];
  const int n0 = blockIdx.x * 32, k0 = blockIdx.y * 32;
  const int tx = threadIdx.x & 31, ty = threadIdx.x >> 5;
  const int n = n0 + tx;
  const float* src = nullptr; int ln = 0, sN = 0;
  if (n < 3072)      { src = qkv_w; ln = n;        sN = 3072; }
  else if (n < 4096) { src = geow;  ln = n - 3072; sN = 1024; }
  else if (n < 4160) { src = w1w;   ln = n - 4096; sN = 64; }
  else if (n < 4224) { src = w2w;   ln = n - 4160; sN = 64; }
  else if (n < 4288) { src = w1r;   ln = n - 4224; sN = 64; }
  else if (n < 4352) { src = w2r;   ln = n - 4288; sN = 64; }
  else if (n < 4368) { src = gatew; ln = n - 4352; sN = 16; }
  #pragma unroll
  for (int i = 0; i < 4; i++)
    tile[ty * 4 + i][tx] = src ? src[(size_t)(k0 + ty * 4 + i) * sN + ln] : 0.f;
  __syncthreads();
  #pragma unroll
  for (int i = 0; i < 4; i++) {
    const int nn = n0 + ty * 4 + i;
    const float s = (nn < 1024) ? 0.125f : 1.f;
    wtall[(size_t)nn * 1024 + k0 + tx] = f2bf(tile[tx][ty * 4 + i] * s);
  }
}

// plain transpose+convert for outw
__global__ __launch_bounds__(256) void tconv_k(const float* __restrict__ W,
                                               short* __restrict__ Wt,
                                               int K, int N) {
  __shared__ float tile[32][33];
  const int k0 = blockIdx.y * 32, n0 = blockIdx.x * 32;
  const int tx = threadIdx.x & 31, ty = threadIdx.x >> 5;
  #pragma unroll
  for (int i = 0; i < 4; i++)
    tile[ty * 4 + i][tx] = W[(size_t)(k0 + ty * 4 + i) * N + n0 + tx];
  __syncthreads();
  #pragma unroll
  for (int i = 0; i < 4; i++)
    Wt[(size_t)(n0 + ty * 4 + i) * K + k0 + tx] = f2bf(tile[tx][ty * 4 + i]);
}

// ---------------------------------------------------------------------------
// m97-style bf16 MFMA GEMM: C[M,N] = A[M,K] @ Bt[N,K]^T + bias
// 128x128 tile, 4 waves, linear LDS [128][32], global_load_lds width-16.
// ---------------------------------------------------------------------------
template<bool BF16_OUT>
__global__ __launch_bounds__(256) void gemm_mfma_k(
    const short* __restrict__ A, const short* __restrict__ Bt,
    const float* __restrict__ bias, void* __restrict__ Cv,
    int M, int N, int K)
{
  __shared__ short As[128][32];
  __shared__ short Bs[128][32];
  const int m0 = blockIdx.y * 128, n0 = blockIdx.x * 128;
  const int tid = threadIdx.x;
  const int wave = tid >> 6, lane = tid & 63;
  const int l15 = lane & 15, lg = lane >> 4;
  const int wm = wave >> 1, wn = wave & 1;
  const int srow = lane >> 2;          // row within wave's 16-row stripe
  const int schk = (lane & 3) * 8;     // k-element offset of this lane's 16B

  const size_t aBase = (size_t)(m0 + wave * 16 + srow) * K + schk;
  const size_t bBase = (size_t)(n0 + wave * 16 + srow) * K + schk;

  fx4 acc[4][4] = {};

  for (int k0 = 0; k0 < K; k0 += 32) {
    __syncthreads();
    GLD16(&A[aBase + k0],              &As[wave * 16][0]);
    GLD16(&A[aBase + (size_t)64 * K + k0], &As[64 + wave * 16][0]);
    GLD16(&Bt[bBase + k0],             &Bs[wave * 16][0]);
    GLD16(&Bt[bBase + (size_t)64 * K + k0], &Bs[64 + wave * 16][0]);
    __syncthreads();
    bf16x8 af[4], bf[4];
    #pragma unroll
    for (int i = 0; i < 4; i++) {
      af[i] = *(const bf16x8*)&As[wm * 64 + i * 16 + l15][8 * lg];
      bf[i] = *(const bf16x8*)&Bs[wn * 64 + i * 16 + l15][8 * lg];
    }
    #pragma unroll
    for (int i = 0; i < 4; i++)
      #pragma unroll
      for (int j = 0; j < 4; j++)
        acc[i][j] = MFMA(af[i], bf[j], acc[i][j]);
  }

  #pragma unroll
  for (int i = 0; i < 4; i++)
    #pragma unroll
    for (int j = 0; j < 4; j++) {
      const int n = n0 + wn * 64 + j * 16 + l15;
      const float bv = bias ? bias[n] : 0.f;
      #pragma unroll
      for (int rg = 0; rg < 4; rg++) {
        const int m = m0 + wm * 64 + i * 16 + lg * 4 + rg;
        const float v = acc[i][j][rg] + bv;
        if constexpr (BF16_OUT)
          ((short*)Cv)[(size_t)m * N + n] = f2bf(v);
        else
          ((float*)Cv)[(size_t)m * N + n] = v;
      }
    }
}

// ---------------------------------------------------------------------------
// Pluecker lines from bf16 slices of allb -> bf16 padded-8 rows
// ---------------------------------------------------------------------------
__device__ __forceinline__ void exterior6(const float a[4], const float c[4], float L[6]) {
  L[0] = a[0]*c[1] - a[1]*c[0];
  L[1] = a[0]*c[2] - a[2]*c[0];
  L[2] = a[0]*c[3] - a[3]*c[0];
  L[3] = a[1]*c[2] - a[2]*c[1];
  L[4] = a[1]*c[3] - a[3]*c[1];
  L[5] = a[2]*c[3] - a[3]*c[2];
}

__device__ __forceinline__ void load4bf(const short* p, float o[4]) {
  const bf16x4 v = *(const bf16x4*)p;
  o[0] = bf2f(v[0]); o[1] = bf2f(v[1]); o[2] = bf2f(v[2]); o[3] = bf2f(v[3]);
}

__global__ void lines_k(const short* __restrict__ allb,
                        const float* __restrict__ incs,
                        short* __restrict__ JWb, short* __restrict__ RLb)
{
  const int idx = blockIdx.x * 256 + threadIdx.x;
  if (idx >= Bc * Tc * Hc) return;
  const int h = idx & 15;
  const int t = (idx >> 4) & (Tc - 1);
  const int b = idx >> 15;
  const size_t row = (size_t)b * Tc + t;
  const size_t lrow = ((size_t)(b * Hc + h) * Tc + t) * 8;

  float a[4] = {0.f, 0.f, 0.f, 0.f};
  float c[4];
  load4bf(&allb[row * NALL + 4160 + h * 4], c);              // w2(x)
  if (t > 0) load4bf(&allb[(row - 1) * NALL + 4096 + h * 4], a);  // w1(x_prev)

  float L[6];
  exterior6(a, c, L);
  float n = sqrtf(L[0]*L[0] + L[1]*L[1] + L[2]*L[2] + L[3]*L[3] + L[4]*L[4] + L[5]*L[5]);
  float inv = 1.f / fmaxf(n, 1e-12f);
  const float s = incs[h];
  bf16x8 jw;
  jw[0] = f2bf( L[5] * inv * s);
  jw[1] = f2bf(-L[4] * inv * s);
  jw[2] = f2bf( L[3] * inv * s);
  jw[3] = f2bf( L[2] * inv * s);
  jw[4] = f2bf(-L[1] * inv * s);
  jw[5] = f2bf( L[0] * inv * s);
  jw[6] = 0; jw[7] = 0;
  *(bf16x8*)&JWb[lrow] = jw;

  load4bf(&allb[row * NALL + 4224 + h * 4], a);              // r1(x)
  load4bf(&allb[row * NALL + 4288 + h * 4], c);              // r2(x)
  exterior6(a, c, L);
  n = sqrtf(L[0]*L[0] + L[1]*L[1] + L[2]*L[2] + L[3]*L[3] + L[4]*L[4] + L[5]*L[5]);
  inv = 1.f / fmaxf(n, 1e-12f);
  bf16x8 rl;
  #pragma unroll
  for (int i = 0; i < 6; i++) rl[i] = f2bf(L[i] * inv);
  rl[6] = 0; rl[7] = 0;
  *(bf16x8*)&RLb[lrow] = rl;
}

__global__ void gate_k(const short* __restrict__ allb, float* __restrict__ gate) {
  const int idx = blockIdx.x * 256 + threadIdx.x;
  if (idx >= Mc) return;
  float ssum = 0.f;
  #pragma unroll
  for (int hh = 0; hh < 16; hh++) {
    const float v = bf2f(allb[(size_t)idx * NALL + 4352 + hh]);
    ssum += 1.f / (1.f + __expf(-v));
  }
  gate[idx] = ssum * (1.f / 16.f);
}

// ---------------------------------------------------------------------------
// Dual flash attention v3 (unchanged structure; reads slices of allb).
// ---------------------------------------------------------------------------
#define LOADK(K0, a0, a1, b0, b1) { \
  const size_t rb0 = (size_t)(b * Tc + (K0) + l15) * NALL + 1024 + h * 64; \
  const size_t rb1 = rb0 + (size_t)16 * NALL; \
  a0 = *(const bf16x8*)&allb[rb0 + lg * 8]; \
  a1 = *(const bf16x8*)&allb[rb0 + 32 + lg * 8]; \
  b0 = *(const bf16x8*)&allb[rb1 + lg * 8]; \
  b1 = *(const bf16x8*)&allb[rb1 + 32 + lg * 8]; }

#define LOADJW(K0, j0, j1) { \
  j0 = z8; j1 = z8; \
  if (lg == 0) { \
    j0 = *(const bf16x8*)&JWb[(size_t)(bh * Tc + (K0) + l15) * 8]; \
    j1 = *(const bf16x8*)&JWb[(size_t)(bh * Tc + (K0) + 16 + l15) * 8]; \
  } }

#define LOADVG(K0, vr, gr) { \
  vr = *(const bf16x8*)&allb[(size_t)(b * Tc + (K0) + kk) * NALL + 2048 + h * 64 + dg]; \
  gr = *(const bf16x8*)&allb[(size_t)(b * Tc + (K0) + kk) * NALL + 3072 + h * 64 + dg]; }

#define STAGEVG(CUR, vr, gr) { \
  _Pragma("unroll") for (int j = 0; j < 8; j++) { \
    const int d = dg + j; \
    const int col = ((kc2 ^ ((d >> 3) & 3)) << 3) | kl2; \
    Vt[CUR][d][col] = vr[j]; Gt[CUR][d][col] = gr[j]; \
  } }

#define COMPUTE(K0, CUR, ka0, ka1, kb0, kb1, jw0, jw1) \
  if ((K0) <= qhi) { \
    fx4 z = {0.f, 0.f, 0.f, 0.f}; \
    fx4 sS0, sS1, sG0, sG1; \
    __builtin_amdgcn_s_setprio(1); \
    sS0 = MFMA(qf0, ka0, z); sS0 = MFMA(qf1, ka1, sS0); \
    sS1 = MFMA(qf0, kb0, z); sS1 = MFMA(qf1, kb1, sS1); \
    sG0 = MFMA(rlf, jw0, z); sG1 = MFMA(rlf, jw1, z); \
    __builtin_amdgcn_s_setprio(0); \
    if ((K0) + KB - 1 > q0 + wave * 16) { \
      const int kg0 = (K0) + l15, kg1 = (K0) + 16 + l15; \
      _Pragma("unroll") for (int r = 0; r < 4; r++) { \
        const int qg = q0 + wave * 16 + lg * 4 + r; \
        if (kg0 > qg) { sS0[r] = -1e30f; sG0[r] = -1e30f; } \
        if (kg1 > qg) { sS1[r] = -1e30f; sG1[r] = -1e30f; } \
      } } \
    _Pragma("unroll") for (int r = 0; r < 4; r++) { \
      const int ql = lg * 4 + r; \
      const float p0 = __expf(sS0[r]); const float p1 = __expf(sS1[r]); \
      lpS[r] += p0 + p1; \
      Ps[wave][ql][l15] = f2bf(p0); Ps[wave][ql][16 + l15] = f2bf(p1); \
      const float g0 = __expf(sG0[r]); const float g1 = __expf(sG1[r]); \
      lpG[r] += g0 + g1; \
      Pg[wave][ql][l15] = f2bf(g0); Pg[wave][ql][16 + l15] = f2bf(g1); \
    } \
    const bf16x8 pa  = *(const bf16x8*)&Ps[wave][l15][8 * lg]; \
    const bf16x8 pga = *(const bf16x8*)&Pg[wave][l15][8 * lg]; \
    __builtin_amdgcn_s_setprio(1); \
    _Pragma("unroll") for (int dt = 0; dt < 4; dt++) { \
      const int dV = dt * 16 + l15; \
      const int swz = 8 * (lg ^ ((dV >> 3) & 3)); \
      accS[dt] = MFMA(pa,  *(const bf16x8*)&Vt[CUR][dV][swz], accS[dt]); \
      accG[dt] = MFMA(pga, *(const bf16x8*)&Gt[CUR][dV][swz], accG[dt]); \
    } \
    __builtin_amdgcn_s_setprio(0); \
  }

__global__ __launch_bounds__(256) void attn3_k(
    const short* __restrict__ allb,  // (4096, 4480) bf16: q|k|v|geo|lines|gate
    const short* __restrict__ RLb,   // (B*H, T, 8) bf16
    const short* __restrict__ JWb,   // (B*H, T, 8) bf16, inc_scale folded
    const float* __restrict__ gate,  // (4096)
    short* __restrict__ combb)       // (4096, 1024) bf16
{
  const int orig = blockIdx.x;        // 0..511
  const int xcd  = orig & 7;
  const int idx  = orig >> 3;         // 0..63
  const int pairIdx = idx & 15;
  const int bh   = xcd + 8 * (idx >> 4);  // 4 bh per XCD
  const int b = bh >> 4, h = bh & 15;
  const int tid = threadIdx.x;
  const int wave = tid >> 6;
  const int lane = tid & 63;
  const int l15 = lane & 15;
  const int lg  = lane >> 4;
  const int kk  = tid >> 3;           // staging k row 0..31
  const int dg  = (tid & 7) * 8;      // staging d group
  const int kc2 = kk >> 3, kl2 = kk & 7;

  __shared__ short Vt[2][64][40];
  __shared__ short Gt[2][64][40];
  __shared__ short Ps[4][16][40];
  __shared__ short Pg[4][16][40];

  const bf16x8 z8 = {0, 0, 0, 0, 0, 0, 0, 0};

  for (int half = 0; half < 2; half++) {
    const int qt = half ? (31 - pairIdx) : pairIdx;
    const int q0 = qt * QB;
    const int nkt = 2 * qt + 2;       // always even
    const int qrow = wave * 16 + l15;
    const int qhi = q0 + wave * 16 + 15;

    const size_t qrb = (size_t)(b * Tc + q0 + qrow) * NALL + h * 64;
    const bf16x8 qf0 = *(const bf16x8*)&allb[qrb + lg * 8];
    const bf16x8 qf1 = *(const bf16x8*)&allb[qrb + 32 + lg * 8];
    bf16x8 rlf = z8;
    if (lg == 0) rlf = *(const bf16x8*)&RLb[(size_t)(bh * Tc + q0 + qrow) * 8];

    fx4 accS[4] = {}, accG[4] = {};
    float lpS[4] = {0.f, 0.f, 0.f, 0.f};
    float lpG[4] = {0.f, 0.f, 0.f, 0.f};

    // prologue: tile 0 into set A
    bf16x8 kA0a, kA1a, kB0a, kB1a, jw0a, jw1a, vrA, grA;
    bf16x8 kA0b, kA1b, kB0b, kB1b, jw0b, jw1b, vrB, grB;
    LOADK(0, kA0a, kA1a, kB0a, kB1a);
    LOADJW(0, jw0a, jw1a);
    LOADVG(0, vrA, grA);

    __syncthreads();   // prev half's readers done before overwriting buf0

    for (int kt = 0; kt < nkt; kt += 2) {
      const int k0a = kt * KB, k0b = k0a + KB;
      STAGEVG(0, vrA, grA);
      LOADK(k0b, kA0b, kA1b, kB0b, kB1b);
      LOADJW(k0b, jw0b, jw1b);
      LOADVG(k0b, vrB, grB);
      __syncthreads();
      COMPUTE(k0a, 0, kA0a, kA1a, kB0a, kB1a, jw0a, jw1a);
      STAGEVG(1, vrB, grB);
      if (kt + 2 < nkt) {
        LOADK(k0b + KB, kA0a, kA1a, kB0a, kB1a);
        LOADJW(k0b + KB, jw0a, jw1a);
        LOADVG(k0b + KB, vrA, grA);
      }
      __syncthreads();
      COMPUTE(k0b, 1, kA0b, kA1b, kB0b, kB1b, jw0b, jw1b);
    }

    // epilogue
    #pragma unroll
    for (int r = 0; r < 4; r++) {
      float ls = lpS[r];
      ls += __shfl_xor(ls, 1); ls += __shfl_xor(ls, 2);
      ls += __shfl_xor(ls, 4); ls += __shfl_xor(ls, 8);
      float lgeo = lpG[r];
      lgeo += __shfl_xor(lgeo, 1); lgeo += __shfl_xor(lgeo, 2);
      lgeo += __shfl_xor(lgeo, 4); lgeo += __shfl_xor(lgeo, 8);
      const int qg = q0 + wave * 16 + lg * 4 + r;
      const float gt = gate[(size_t)b * Tc + qg];
      const float invS = (1.f - gt) / ls;
      const float invG = gt / lgeo;
      #pragma unroll
      for (int dt = 0; dt < 4; dt++) {
        const float o = accS[dt][r] * invS + accG[dt][r] * invG;
        combb[(size_t)(b * Tc + qg) * 1024 + h * 64 + dt * 16 + l15] = f2bf(o);
      }
    }
  }
}

// ---------------------------------------------------------------------------
extern "C" void kernel_launch(void* const* d_in, const int* in_sizes, int n_in,
                              void* d_out, int out_size, void* d_ws, size_t ws_size,
                              hipStream_t stream) {
  (void)in_sizes; (void)n_in; (void)out_size; (void)ws_size;
  const float* x     = (const float*)d_in[0];
  const float* qkv_w = (const float*)d_in[1];
  const float* qkv_b = (const float*)d_in[2];
  const float* w1w   = (const float*)d_in[3];
  const float* w2w   = (const float*)d_in[4];
  const float* w1r   = (const float*)d_in[5];
  const float* w2r   = (const float*)d_in[6];
  const float* geow  = (const float*)d_in[7];
  const float* geob  = (const float*)d_in[8];
  const float* gatew = (const float*)d_in[9];
  const float* gateb = (const float*)d_in[10];
  const float* incs  = (const float*)d_in[11];
  const float* outw  = (const float*)d_in[12];
  const float* outb  = (const float*)d_in[13];
  float* out = (float*)d_out;

  char* p = (char*)d_ws;
  short* xb    = (short*)p;  p += (size_t)4096 * 1024 * 2;   // 8 MB
  short* wtall = (short*)p;  p += (size_t)NALL * 1024 * 2;   // 9.2 MB
  short* allb  = (short*)p;  p += (size_t)4096 * NALL * 2;   // 36.7 MB
  short* combb = (short*)p;  p += (size_t)4096 * 1024 * 2;   // 8 MB
  short* wtout = (short*)p;  p += (size_t)1024 * 1024 * 2;   // 2 MB
  short* JWb   = (short*)p;  p += (size_t)32 * 2048 * 8 * 2; // 1 MB
  short* RLb   = (short*)p;  p += (size_t)32 * 2048 * 8 * 2; // 1 MB
  float* ball  = (float*)p;  p += (size_t)NALL * 4;
  float* gatev = (float*)p;  p += (size_t)4096 * 4;

  const dim3 blk(256);

  f2b_k<<<dim3(4096), blk, 0, stream>>>(x, xb);
  biasall_k<<<dim3((NALL + 255) / 256), blk, 0, stream>>>(qkv_b, geob, gateb, ball);
  tconv_all_k<<<dim3(NALL / 32, 32), blk, 0, stream>>>(qkv_w, geow, w1w, w2w, w1r, w2r, gatew, wtall);
  tconv_k<<<dim3(32, 32), blk, 0, stream>>>(outw, wtout, 1024, 1024);

  // merged projection GEMM: (4096 x 1024) @ (1024 x 4480) -> allb
  gemm_mfma_k<true><<<dim3(NALL / 128, 32), blk, 0, stream>>>(xb, wtall, ball, allb, 4096, NALL, 1024);

  lines_k<<<dim3((Bc * Tc * Hc + 255) / 256), blk, 0, stream>>>(allb, incs, JWb, RLb);
  gate_k<<<dim3((Mc + 255) / 256), blk, 0, stream>>>(allb, gatev);

  attn3_k<<<dim3(512), blk, 0, stream>>>(allb, RLb, JWb, gatev, combb);

  // final projection -> fp32 output
  gemm_mfma_k<false><<<dim3(8, 32), blk, 0, stream>>>(combb, wtout, outb, (void*)out, 4096, 1024, 1024);
}